// Round 11
// baseline (37.009 us; speedup 1.0000x reference)
//
#include <hip/hip_runtime.h>

#define NB 4
#define NV 256
#define NF 256
#define IMG 128
#define STR 36   // floats per face-PAIR record: 4 bbox + 16 slots x 2

typedef float v2f __attribute__((ext_vector_type(2)));
typedef float v4f __attribute__((ext_vector_type(4)));

__device__ __forceinline__ float rcpf(float x) { return __builtin_amdgcn_rcpf(x); }
__device__ __forceinline__ float ex2(float x)  { return __builtin_amdgcn_exp2f(x); }
__device__ __forceinline__ float med01(float x) { return __builtin_amdgcn_fmed3f(x, 0.0f, 1.0f); }
__device__ __forceinline__ v2f med01_2(v2f v) { return (v2f){ med01(v.x), med01(v.y) }; }
__device__ __forceinline__ v2f fma2(v2f a, v2f b, v2f c) { return __builtin_elementwise_fma(a, b, c); }
__device__ __forceinline__ v2f lo2(v4f q) { return __builtin_shufflevector(q, q, 0, 1); }
__device__ __forceinline__ v2f hi2(v4f q) { return __builtin_shufflevector(q, q, 2, 3); }

#define SCV   120.11224139682566f    // sqrt((1/SIGMA)*log2(e))
#define ISC2  6.931471805599453e-05f // 1/KSIG
#define KGAMV 14.426950408889634f    // (1/GAMMA)*log2(e)

// pair record (pair p of batch b at ws + (b*128+p)*STR):
//   [0..3]  union bbox (wmin, wmax, hmin, hmax; pixel units, 4px margin)
//   [4+2k+j] slot k of face-parity j:
//   k: 0 a0x*SC 1 a0y*SC 2 e01x*SC 3 e01y*SC 4 e12x*SC 5 e12y*SC
//      6 ib01' 7 ib12' 8 ib20' 9 idn' 10 z0 11 z1 12 z2 13 cr 14 cg 15 cb

__global__ void prep_faces(const float* __restrict__ verts,
                           const int* __restrict__ faces,
                           const float* __restrict__ colors,
                           const float* __restrict__ eye,
                           float* __restrict__ ws)
{
    __shared__ float    sRec[256][16];
    __shared__ float4   sBB[256];
    __shared__ unsigned sKey[256];

    const int b = blockIdx.x;      // 0..3
    const int f = threadIdx.x;     // 0..255

    const float fpj = 1.7320508075688772f;
    const float p22 = -1.0202020202020203f;
    const float p23 = -0.20202020202020202f;

    float ex = eye[b*3+0], ey = eye[b*3+1], ez = eye[b*3+2];
    float en  = sqrtf(ex*ex + ey*ey + ez*ez);
    float izn = 1.0f / (en + 1e-8f);
    float zx = ex*izn, zy = ey*izn, zz = ez*izn;
    float cn  = sqrtf(zz*zz + zx*zx);
    float ixn = 1.0f / (cn + 1e-8f);
    float xx = zz*ixn, xy = 0.0f, xz = -zx*ixn;
    float yx = zy*xz - zz*xy;
    float yy = zz*xx - zx*xz;
    float yz = zx*xy - zy*xx;
    float tx = -(xx*ex + xy*ey + xz*ez);
    float ty = -(yx*ex + yy*ey + yz*ez);
    float tz = -(zx*ex + zy*ey + zz*ez);

    int i0 = faces[f*3+0], i1 = faces[f*3+1], i2 = faces[f*3+2];
    int idx[3] = { i0, i1, i2 };

    float ax[3], ay[3], az[3];
#pragma unroll
    for (int k = 0; k < 3; ++k) {
        const float* v = verts + (b*NV + idx[k])*3;
        float vx = v[0], vy = v[1], vz = v[2];
        float cx  = fpj*(xx*vx + xy*vy + xz*vz + tx);
        float cyv = fpj*(yx*vx + yy*vy + yz*vz + ty);
        float zv  = zx*vx + zy*vy + zz*vz + tz;
        float cz  = p22*zv + p23;
        float cw  = -zv;
        float iw  = 1.0f / (cw + 1e-8f);
        ax[k] = cx*iw; ay[k] = cyv*iw; az[k] = cz*iw;
    }

    float a0x = ax[0], a0y = ay[0];
    float a1x = ax[1], a1y = ay[1];
    float a2x = ax[2], a2y = ay[2];

    float e01x = a1x - a0x, e01y = a1y - a0y;
    float e12x = a2x - a1x, e12y = a2y - a1y;
    float e20x = a0x - a2x, e20y = a0y - a2y;

    float area  = e01x*(a2y - a0y) - e01y*(a2x - a0x);
    float denom = area + (area >= 0.0f ? 1e-12f : -1e-12f);
    float idn   = 1.0f / denom;

    float ib01 = 1.0f / (e01x*e01x + e01y*e01y + 1e-12f);
    float ib12 = 1.0f / (e12x*e12x + e12y*e12y + 1e-12f);
    float ib20 = 1.0f / (e20x*e20x + e20y*e20y + 1e-12f);

    const float third = (1.0f/3.0f);
    float cr = (colors[(b*NV+i0)*3+0] + colors[(b*NV+i1)*3+0] + colors[(b*NV+i2)*3+0]) * third;
    float cg = (colors[(b*NV+i0)*3+1] + colors[(b*NV+i1)*3+1] + colors[(b*NV+i2)*3+1]) * third;
    float cb = (colors[(b*NV+i0)*3+2] + colors[(b*NV+i1)*3+2] + colors[(b*NV+i2)*3+2]) * third;

    sRec[f][ 0]=a0x*SCV;   sRec[f][ 1]=a0y*SCV;
    sRec[f][ 2]=e01x*SCV;  sRec[f][ 3]=e01y*SCV;
    sRec[f][ 4]=e12x*SCV;  sRec[f][ 5]=e12y*SCV;
    sRec[f][ 6]=ib01*ISC2; sRec[f][ 7]=ib12*ISC2; sRec[f][ 8]=ib20*ISC2;
    sRec[f][ 9]=idn*ISC2;
    sRec[f][10]=az[0]; sRec[f][11]=az[1]; sRec[f][12]=az[2];
    sRec[f][13]=cr;    sRec[f][14]=cg;    sRec[f][15]=cb;

    // pixel-space bbox with 4px margin (safe cutoff 3.02px at sigma=1e-4)
    float xmn = fminf(fminf(a0x, a1x), a2x);
    float xmx = fmaxf(fmaxf(a0x, a1x), a2x);
    float ymn = fminf(fminf(a0y, a1y), a2y);
    float ymx = fmaxf(fmaxf(a0y, a1y), a2y);
    float4 bb = make_float4((xmn + 0.9375f)*64.0f - 0.5f,   // wmin
                            (xmx + 1.0625f)*64.0f - 0.5f,   // wmax
                            (0.9375f - ymx)*64.0f - 0.5f,   // hmin
                            (1.0625f - ymn)*64.0f - 0.5f);  // hmax
    sBB[f] = bb;

    // Morton key of bbox center (8x8px tile units, 4 bits each), unique via face id
    {
        float cxp = 0.5f*(bb.x + bb.y) * 0.125f;
        float cyp = 0.5f*(bb.z + bb.w) * 0.125f;
        int qx = min(max((int)cxp, 0), 15);
        int qy = min(max((int)cyp, 0), 15);
        unsigned m = 0;
#pragma unroll
        for (int k = 0; k < 4; ++k)
            m |= (((qx >> k) & 1u) << (2*k)) | (((qy >> k) & 1u) << (2*k + 1));
        sKey[f] = (m << 8) | (unsigned)f;
    }
    __syncthreads();

    // bitonic sort of 256 keys (deterministic: keys unique)
    for (int k = 2; k <= 256; k <<= 1) {
        for (int j = k >> 1; j > 0; j >>= 1) {
            int ixj = f ^ j;
            if (ixj > f) {
                unsigned va = sKey[f], vb = sKey[ixj];
                bool up = ((f & k) == 0);
                if ((va > vb) == up) { sKey[f] = vb; sKey[ixj] = va; }
            }
            __syncthreads();
        }
    }

    // thread f = sorted position; pair = f>>1, parity = f&1
    {
        const int i   = (int)(sKey[f] & 255u);
        const int par = f & 1;
        float* o = ws + (b*128 + (f >> 1))*STR;
        if (par == 0) {
            const int i2 = (int)(sKey[f | 1] & 255u);
            float4 u = sBB[i], v = sBB[i2];
            o[0] = fminf(u.x, v.x);
            o[1] = fmaxf(u.y, v.y);
            o[2] = fminf(u.z, v.z);
            o[3] = fmaxf(u.w, v.w);
        }
#pragma unroll
        for (int k = 0; k < 16; ++k)
            o[4 + 2*k + par] = sRec[i][k];
    }
}

// grid 1024 = b*256 + tile(8x8px); block (64,8): lane = pixel of tile,
// wave cy processes pairs {cy, cy+8, ..., cy+120} (strided over Morton order)
__launch_bounds__(512, 6)
__global__ void raster(const float* __restrict__ ws, float* __restrict__ out)
{
    __shared__ float4 sFD4[1152];               // 18KB: 128 pairs x 36 floats
    float* sFD = (float*)sFD4;

    const int t   = threadIdx.x;   // 0..63
    const int cy  = threadIdx.y;   // 0..7
    const int bid = blockIdx.x;
    const int b    = bid >> 8;
    const int tile = bid & 255;
    const int tx0 = (tile & 15) << 3;
    const int ty0 = (tile >> 4) << 3;

    // stage per-batch pair table: 1152 float4
    {
        const float4* src = (const float4*)(ws + b*(128*STR));
        const int tid = (cy << 6) + t;          // 0..511
        for (int k = tid; k < 1152; k += 512) sFD4[k] = src[k];
    }
    __syncthreads();

    const int w = tx0 + (t & 7);
    const int h = ty0 + (t >> 3);
    const float xs = ((w + 0.5f) * (1.0f/64.0f) - 1.0f) * SCV;
    const float ys = (1.0f - (h + 0.5f) * (1.0f/64.0f)) * SCV;
    const v2f PX = { xs, xs }, PY = { ys, ys };

    const float tX0f = (float)tx0, tX1f = (float)(tx0 + 7);
    const float tY0f = (float)ty0, tY1f = (float)(ty0 + 7);

    const v2f KGH_NEG = { -0.5f*KGAMV, -0.5f*KGAMV };
    const v2f KGH_POS = {  0.5f*KGAMV,  0.5f*KGAMV };
    const v2f ONE2 = { 1.0f, 1.0f };
    const v2f EPS2 = { 1e-8f, 1e-8f };

    v2f aP = ONE2, aS = {0,0}, aR0 = {0,0}, aR1 = {0,0}, aR2 = {0,0};

    for (int i = 0; i < 16; ++i) {
        const int p = cy + (i << 3);            // strided pair assignment
        const float* c = sFD + p*STR;
        const v4f bb = *(const v4f*)c;
        // wave-uniform cull: pair's union bbox vs this block's 8x8 tile
        if (bb.x <= tX1f && bb.y >= tX0f && bb.z <= tY1f && bb.w >= tY0f) {
            const v4f q0 = *(const v4f*)(c +  4);
            const v4f q1 = *(const v4f*)(c +  8);
            const v4f q2 = *(const v4f*)(c + 12);
            const v4f q3 = *(const v4f*)(c + 16);
            const v4f q4 = *(const v4f*)(c + 20);
            const v4f q5 = *(const v4f*)(c + 24);
            const v4f q6 = *(const v4f*)(c + 28);
            const v4f q7 = *(const v4f*)(c + 32);
            v2f a0x = lo2(q0), a0y = hi2(q0);
            v2f e01x = lo2(q1), e01y = hi2(q1);
            v2f e12x = lo2(q2), e12y = hi2(q2);
            v2f ib01 = lo2(q3), ib12 = hi2(q3);
            v2f ib20 = lo2(q4), idn  = hi2(q4);
            v2f z0 = lo2(q5), z1 = hi2(q5);
            v2f z2 = lo2(q6), cr = hi2(q6);
            v2f cg = lo2(q7), cb = hi2(q7);

            v2f e20x = -(e01x + e12x), e20y = -(e01y + e12y);
            v2f g01x = e01x*ib01, g01y = e01y*ib01;
            v2f g12x = e12x*ib12, g12y = e12y*ib12;
            v2f g20x = e20x*ib20, g20y = e20y*ib20;

            // PH1: barycentrics (b2 = 1-b0-b1) + signed scaled sq-distance
            v2f pa0x = PX - a0x, pa0y = PY - a0y;
            v2f pa1x = pa0x - e01x, pa1y = pa0y - e01y;
            v2f pa2x = pa0x + e20x, pa2y = pa0y + e20y;
            v2f b0 = fma2(-e12y, pa1x, e12x*pa1y) * idn;
            v2f b1 = fma2(-e20y, pa2x, e20x*pa2y) * idn;
            v2f b2 = (ONE2 - b0) - b1;

            v2f tt = med01_2(fma2(pa0x, g01x, pa0y*g01y));
            v2f dx = fma2(-tt, e01x, pa0x);
            v2f dy = fma2(-tt, e01y, pa0y);
            v2f ddA = fma2(dx, dx, dy*dy);
            tt = med01_2(fma2(pa1x, g12x, pa1y*g12y));
            dx = fma2(-tt, e12x, pa1x);
            dy = fma2(-tt, e12y, pa1y);
            v2f ddB = fma2(dx, dx, dy*dy);
            tt = med01_2(fma2(pa2x, g20x, pa2y*g20y));
            dx = fma2(-tt, e20x, pa2x);
            dy = fma2(-tt, e20y, pa2y);
            v2f ddC = fma2(dx, dx, dy*dy);

            v2f dd = __builtin_elementwise_min(__builtin_elementwise_min(ddA, ddB), ddC);
            v2f mx = __builtin_elementwise_max(__builtin_elementwise_max(-b0, -b1), -b2);
            v2f q  = { copysignf(dd.x, mx.x), copysignf(dd.y, mx.y) };

            // PH2: sigmoid + softmax weight
            v2f e2 = { ex2(q.x), ex2(q.y) };
            v2f den = e2 + ONE2;
            v2f prob = { rcpf(den.x), rcpf(den.y) };
            aP = fma2(-prob, aP, aP);

            v2f bc0 = med01_2(b0), bc1 = med01_2(b1), bc2 = med01_2(b2);
            v2f s = (bc0 + bc1) + (bc2 + EPS2);
            v2f zs = fma2(bc0, z0, fma2(bc1, z1, bc2*z2));
            v2f irs = { rcpf(s.x), rcpf(s.y) };
            v2f zq = fma2(zs*irs, KGH_NEG, KGH_POS);
            v2f ez = { ex2(__builtin_amdgcn_fmed3f(zq.x, 0.0f, KGAMV)),
                       ex2(__builtin_amdgcn_fmed3f(zq.y, 0.0f, KGAMV)) };
            v2f wgt = prob * ez;
            aS  = aS + wgt;
            aR0 = fma2(wgt, cr, aR0);
            aR1 = fma2(wgt, cg, aR1);
            aR2 = fma2(wgt, cb, aR2);
        }
    }

    // alias reduction arrays into the table LDS
    __syncthreads();
    float* red = sFD;   // [5][8][64] = 2560 floats < 4608
    red[(0*8 + cy)*64 + t] = aP.x * aP.y;
    red[(1*8 + cy)*64 + t] = aS.x + aS.y;
    red[(2*8 + cy)*64 + t] = aR0.x + aR0.y;
    red[(3*8 + cy)*64 + t] = aR1.x + aR1.y;
    red[(4*8 + cy)*64 + t] = aR2.x + aR2.y;
    __syncthreads();

    if (cy == 0) {
        float P = 1.0f, St = 0.0f, r0 = 0.0f, r1 = 0.0f, r2 = 0.0f;
#pragma unroll
        for (int c2 = 0; c2 < 8; ++c2) {
            P  *= red[(0*8 + c2)*64 + t];
            St += red[(1*8 + c2)*64 + t];
            r0 += red[(2*8 + c2)*64 + t];
            r1 += red[(3*8 + c2)*64 + t];
            r2 += red[(4*8 + c2)*64 + t];
        }
        float iden = rcpf(St + 1.0f);   // background weight = exp2(0) = 1

        const int pix = h*IMG + w;
        out[b*16384 + pix] = 1.0f - P;
        float* rgb = out + 65536;
        rgb[(b*3 + 0)*16384 + pix] = r0 * iden;
        rgb[(b*3 + 1)*16384 + pix] = r1 * iden;
        rgb[(b*3 + 2)*16384 + pix] = r2 * iden;
    }
}

extern "C" void kernel_launch(void* const* d_in, const int* in_sizes, int n_in,
                              void* d_out, int out_size, void* d_ws, size_t ws_size,
                              hipStream_t stream)
{
    const float* verts  = (const float*)d_in[0];
    const int*   faces  = (const int*)d_in[1];
    const float* colors = (const float*)d_in[2];
    const float* eye    = (const float*)d_in[3];
    float* out = (float*)d_out;
    float* ws  = (float*)d_ws;   // 4*128 pairs * 36 floats = 72 KB

    hipLaunchKernelGGL(prep_faces, dim3(4),    dim3(256),   0, stream,
                       verts, faces, colors, eye, ws);
    hipLaunchKernelGGL(raster,     dim3(1024), dim3(64, 8), 0, stream, ws, out);
}

// Round 12
// 33.346 us; speedup vs baseline: 1.1098x; 1.1098x over previous
//
#include <hip/hip_runtime.h>

#define NB 4
#define NV 256
#define NF 256
#define IMG 128
#define STR 32   // floats per face-PAIR record (16 slots x 2, 128B)

typedef float v2f __attribute__((ext_vector_type(2)));
typedef float v4f __attribute__((ext_vector_type(4)));

__device__ __forceinline__ float rcpf(float x) { return __builtin_amdgcn_rcpf(x); }
__device__ __forceinline__ float ex2(float x)  { return __builtin_amdgcn_exp2f(x); }
__device__ __forceinline__ float med01(float x) { return __builtin_amdgcn_fmed3f(x, 0.0f, 1.0f); }
__device__ __forceinline__ v2f med01_2(v2f v) { return (v2f){ med01(v.x), med01(v.y) }; }
__device__ __forceinline__ v2f fma2(v2f a, v2f b, v2f c) { return __builtin_elementwise_fma(a, b, c); }
__device__ __forceinline__ v2f lo2(v4f q) { return __builtin_shufflevector(q, q, 0, 1); }
__device__ __forceinline__ v2f hi2(v4f q) { return __builtin_shufflevector(q, q, 2, 3); }

#define SCV   120.11224139682566f    // sqrt((1/SIGMA)*log2(e))
#define ISC2  6.931471805599453e-05f // 1/KSIG
#define KGAMV 14.426950408889634f    // (1/GAMMA)*log2(e)

// pair-interleaved record, slot k of face f at [2k + (f&1)]:
//  0 a0x*SC 1 a0y*SC | 2 e01x*SC 3 e01y*SC | 4 e12x*SC 5 e12y*SC | 6 ib01' 7 ib12'
//  8 ib20' 9 idn'    | 10 z0 11 z1 | 12 z2 13 cr | 14 cg 15 cb     (' = /KSIG)

__global__ void prep_faces(const float* __restrict__ verts,
                           const int* __restrict__ faces,
                           const float* __restrict__ colors,
                           const float* __restrict__ eye,
                           float* __restrict__ ws)
{
    const int b = blockIdx.x;      // 0..3
    const int f = threadIdx.x;     // 0..255

    const float fpj = 1.7320508075688772f;
    const float p22 = -1.0202020202020203f;
    const float p23 = -0.20202020202020202f;

    float ex = eye[b*3+0], ey = eye[b*3+1], ez = eye[b*3+2];
    float en  = sqrtf(ex*ex + ey*ey + ez*ez);
    float izn = 1.0f / (en + 1e-8f);
    float zx = ex*izn, zy = ey*izn, zz = ez*izn;
    float cn  = sqrtf(zz*zz + zx*zx);
    float ixn = 1.0f / (cn + 1e-8f);
    float xx = zz*ixn, xy = 0.0f, xz = -zx*ixn;
    float yx = zy*xz - zz*xy;
    float yy = zz*xx - zx*xz;
    float yz = zx*xy - zy*xx;
    float tx = -(xx*ex + xy*ey + xz*ez);
    float ty = -(yx*ex + yy*ey + yz*ez);
    float tz = -(zx*ex + zy*ey + zz*ez);

    int i0 = faces[f*3+0], i1 = faces[f*3+1], i2 = faces[f*3+2];
    int idx[3] = { i0, i1, i2 };

    float ax[3], ay[3], az[3];
#pragma unroll
    for (int k = 0; k < 3; ++k) {
        const float* v = verts + (b*NV + idx[k])*3;
        float vx = v[0], vy = v[1], vz = v[2];
        float cx  = fpj*(xx*vx + xy*vy + xz*vz + tx);
        float cyv = fpj*(yx*vx + yy*vy + yz*vz + ty);
        float zv  = zx*vx + zy*vy + zz*vz + tz;
        float cz  = p22*zv + p23;
        float cw  = -zv;
        float iw  = 1.0f / (cw + 1e-8f);
        ax[k] = cx*iw; ay[k] = cyv*iw; az[k] = cz*iw;
    }

    float a0x = ax[0], a0y = ay[0];
    float a1x = ax[1], a1y = ay[1];
    float a2x = ax[2], a2y = ay[2];

    float e01x = a1x - a0x, e01y = a1y - a0y;
    float e12x = a2x - a1x, e12y = a2y - a1y;
    float e20x = a0x - a2x, e20y = a0y - a2y;

    float area  = e01x*(a2y - a0y) - e01y*(a2x - a0x);
    float denom = area + (area >= 0.0f ? 1e-12f : -1e-12f);
    float idn   = 1.0f / denom;

    float ib01 = 1.0f / (e01x*e01x + e01y*e01y + 1e-12f);
    float ib12 = 1.0f / (e12x*e12x + e12y*e12y + 1e-12f);
    float ib20 = 1.0f / (e20x*e20x + e20y*e20y + 1e-12f);

    const float third = (1.0f/3.0f);
    float cr = (colors[(b*NV+i0)*3+0] + colors[(b*NV+i1)*3+0] + colors[(b*NV+i2)*3+0]) * third;
    float cg = (colors[(b*NV+i0)*3+1] + colors[(b*NV+i1)*3+1] + colors[(b*NV+i2)*3+1]) * third;
    float cb = (colors[(b*NV+i0)*3+2] + colors[(b*NV+i1)*3+2] + colors[(b*NV+i2)*3+2]) * third;

    float* o = ws + (b*128 + (f >> 1))*STR + (f & 1);
    o[ 0]=a0x*SCV;   o[ 2]=a0y*SCV;
    o[ 4]=e01x*SCV;  o[ 6]=e01y*SCV;
    o[ 8]=e12x*SCV;  o[10]=e12y*SCV;
    o[12]=ib01*ISC2; o[14]=ib12*ISC2; o[16]=ib20*ISC2;
    o[18]=idn*ISC2;
    o[20]=az[0]; o[22]=az[1]; o[24]=az[2];
    o[26]=cr;   o[28]=cg;   o[30]=cb;
}

// grid 1024 = b*256 + tile(8x8px); block (64,8): lane = pixel, wave cy = 16-pair chunk
__launch_bounds__(512, 4)
__global__ void raster(const float* __restrict__ ws, float* __restrict__ out)
{
    __shared__ float sFD[4096];   // 16KB table; reduction arrays aliased after loop

    const int t   = threadIdx.x;   // 0..63
    const int cy  = threadIdx.y;   // 0..7
    const int bid = blockIdx.x;
    const int b    = bid >> 8;
    const int tile = bid & 255;
    const int tx0 = (tile & 15) << 3;
    const int ty0 = (tile >> 4) << 3;

    // stage per-batch face table: 4096 floats = 1024 float4, 2 per thread
    {
        const float4* src = (const float4*)(ws + (b << 12));
        float4* dst = (float4*)sFD;
        int tid = (cy << 6) + t;    // 0..511
        dst[tid]       = src[tid];
        dst[tid + 512] = src[tid + 512];
    }
    __syncthreads();

    const int w = tx0 + (t & 7);
    const int h = ty0 + (t >> 3);
    const float xs = ((w + 0.5f) * (1.0f/64.0f) - 1.0f) * SCV;
    const float ys = (1.0f - (h + 0.5f) * (1.0f/64.0f)) * SCV;
    const v2f PX = { xs, xs }, PY = { ys, ys };

    const v2f KGH_NEG = { -0.5f*KGAMV, -0.5f*KGAMV };
    const v2f KGH_POS = {  0.5f*KGAMV,  0.5f*KGAMV };
    const v2f ONE2 = { 1.0f, 1.0f };
    const v2f EPS2 = { 1e-8f, 1e-8f };

    const float* fc = sFD + (cy << 4)*STR;   // this wave's 16 pairs

    v2f aP = ONE2, aS = {0,0}, aR0 = {0,0}, aR1 = {0,0}, aR2 = {0,0};

    // FULL unroll: all 128 ds_read_b128 get compile-time offsets off one base;
    // the scheduler can hoist loads across iterations with counted lgkmcnt waits
    // instead of a load->waitcnt(0)->compute drain every iteration.
#pragma unroll
    for (int i = 0; i < 16; ++i) {
        const float* c = fc + i*STR;
        v4f q0 = *(const v4f*)(c +  0);
        v4f q1 = *(const v4f*)(c +  4);
        v4f q2 = *(const v4f*)(c +  8);
        v4f q3 = *(const v4f*)(c + 12);
        v4f q4 = *(const v4f*)(c + 16);
        v4f q5 = *(const v4f*)(c + 20);
        v4f q6 = *(const v4f*)(c + 24);
        v4f q7 = *(const v4f*)(c + 28);
        v2f a0x = lo2(q0), a0y = hi2(q0);
        v2f e01x = lo2(q1), e01y = hi2(q1);
        v2f e12x = lo2(q2), e12y = hi2(q2);
        v2f ib01 = lo2(q3), ib12 = hi2(q3);
        v2f ib20 = lo2(q4), idn  = hi2(q4);
        v2f z0 = lo2(q5), z1 = hi2(q5);
        v2f z2 = lo2(q6), cr = hi2(q6);
        v2f cg = lo2(q7), cb = hi2(q7);

        v2f e20x = -(e01x + e12x), e20y = -(e01y + e12y);
        v2f g01x = e01x*ib01, g01y = e01y*ib01;
        v2f g12x = e12x*ib12, g12y = e12y*ib12;
        v2f g20x = e20x*ib20, g20y = e20y*ib20;

        // PH1: barycentrics (b2 = 1-b0-b1) + signed scaled sq-distance
        v2f pa0x = PX - a0x, pa0y = PY - a0y;
        v2f pa1x = pa0x - e01x, pa1y = pa0y - e01y;
        v2f pa2x = pa0x + e20x, pa2y = pa0y + e20y;
        v2f b0 = fma2(-e12y, pa1x, e12x*pa1y) * idn;
        v2f b1 = fma2(-e20y, pa2x, e20x*pa2y) * idn;
        v2f b2 = (ONE2 - b0) - b1;

        v2f tt = med01_2(fma2(pa0x, g01x, pa0y*g01y));
        v2f dx = fma2(-tt, e01x, pa0x);
        v2f dy = fma2(-tt, e01y, pa0y);
        v2f ddA = fma2(dx, dx, dy*dy);
        tt = med01_2(fma2(pa1x, g12x, pa1y*g12y));
        dx = fma2(-tt, e12x, pa1x);
        dy = fma2(-tt, e12y, pa1y);
        v2f ddB = fma2(dx, dx, dy*dy);
        tt = med01_2(fma2(pa2x, g20x, pa2y*g20y));
        dx = fma2(-tt, e20x, pa2x);
        dy = fma2(-tt, e20y, pa2y);
        v2f ddC = fma2(dx, dx, dy*dy);

        v2f dd = __builtin_elementwise_min(__builtin_elementwise_min(ddA, ddB), ddC);
        v2f mx = __builtin_elementwise_max(__builtin_elementwise_max(-b0, -b1), -b2);
        v2f q  = { copysignf(dd.x, mx.x), copysignf(dd.y, mx.y) };

        // PH2: sigmoid + softmax weight
        v2f e2 = { ex2(q.x), ex2(q.y) };
        v2f den = e2 + ONE2;
        v2f prob = { rcpf(den.x), rcpf(den.y) };
        aP = fma2(-prob, aP, aP);

        v2f bc0 = med01_2(b0), bc1 = med01_2(b1), bc2 = med01_2(b2);
        v2f s = (bc0 + bc1) + (bc2 + EPS2);
        v2f zs = fma2(bc0, z0, fma2(bc1, z1, bc2*z2));
        v2f irs = { rcpf(s.x), rcpf(s.y) };
        v2f zq = fma2(zs*irs, KGH_NEG, KGH_POS);
        v2f ez = { ex2(__builtin_amdgcn_fmed3f(zq.x, 0.0f, KGAMV)),
                   ex2(__builtin_amdgcn_fmed3f(zq.y, 0.0f, KGAMV)) };
        v2f wgt = prob * ez;
        aS  = aS + wgt;
        aR0 = fma2(wgt, cr, aR0);
        aR1 = fma2(wgt, cg, aR1);
        aR2 = fma2(wgt, cb, aR2);
    }

    // alias reduction arrays into the table LDS
    __syncthreads();
    float* red = sFD;   // [5][8][64] = 10KB
    red[(0*8 + cy)*64 + t] = aP.x * aP.y;
    red[(1*8 + cy)*64 + t] = aS.x + aS.y;
    red[(2*8 + cy)*64 + t] = aR0.x + aR0.y;
    red[(3*8 + cy)*64 + t] = aR1.x + aR1.y;
    red[(4*8 + cy)*64 + t] = aR2.x + aR2.y;
    __syncthreads();

    if (cy == 0) {
        float P = 1.0f, St = 0.0f, r0 = 0.0f, r1 = 0.0f, r2 = 0.0f;
#pragma unroll
        for (int c2 = 0; c2 < 8; ++c2) {
            P  *= red[(0*8 + c2)*64 + t];
            St += red[(1*8 + c2)*64 + t];
            r0 += red[(2*8 + c2)*64 + t];
            r1 += red[(3*8 + c2)*64 + t];
            r2 += red[(4*8 + c2)*64 + t];
        }
        float iden = rcpf(St + 1.0f);   // background weight = exp2(0) = 1

        const int pix = h*IMG + w;
        out[b*16384 + pix] = 1.0f - P;
        float* rgb = out + 65536;
        rgb[(b*3 + 0)*16384 + pix] = r0 * iden;
        rgb[(b*3 + 1)*16384 + pix] = r1 * iden;
        rgb[(b*3 + 2)*16384 + pix] = r2 * iden;
    }
}

extern "C" void kernel_launch(void* const* d_in, const int* in_sizes, int n_in,
                              void* d_out, int out_size, void* d_ws, size_t ws_size,
                              hipStream_t stream)
{
    const float* verts  = (const float*)d_in[0];
    const int*   faces  = (const int*)d_in[1];
    const float* colors = (const float*)d_in[2];
    const float* eye    = (const float*)d_in[3];
    float* out = (float*)d_out;
    float* ws  = (float*)d_ws;   // 64 KB face records

    hipLaunchKernelGGL(prep_faces, dim3(4),    dim3(256),   0, stream,
                       verts, faces, colors, eye, ws);
    hipLaunchKernelGGL(raster,     dim3(1024), dim3(64, 8), 0, stream, ws, out);
}